// Round 17
// baseline (95.327 us; speedup 1.0000x reference)
//
#include <hip/hip_runtime.h>

// Chamfer distance: B=8, N=M=8192, D=3, fp32, via bf16 split-precision MFMA.
// R24: R23 ((256,1)) null: VGPR_Count stuck 76 (= half the arch alloc;
//   counter reads arch-regs/2 across all rounds: R8 64@128cap, R14 48@96,
//   R23 76@154) -> no AGPR copies; 8th scheduling theory dead. Cross-round
//   audit instead: R21's one-pass main (HALF the MFMAs + HALF the L2
//   traffic) ran ~= R19's 41.5 -> large WORK-INDEPENDENT wall component.
//   Common fixed cost: 512-1024 blocks all atomicAdd the SAME out[0], all
//   finishing ~simultaneously -> serialized RMW on one L2 line (~40-80cy
//   each) = 8-17us kernel tail (endpgm drains vmcnt; waves wait on their
//   atomic). Reconciles R15 vs R16: R15 (1024 blk, tail~17) compute ~26.7
//   — best of all — masked by doubled tail.
//   Changes: (1) R15 geometry verbatim (PPW=2, 4 waves/SIMD, 1024 blocks,
//   copy-free x2 ping-pong — best compute core). (2) NO atomics: block
//   stores unscaled bsum to part[bid]; 1-block chamfer_final (~2us) sums
//   1024 floats -> out[0]. Discriminator: partial >=40 -> tail theory dead
//   -> practical plateau declared next round.

#define B_DIM 8
#define N_DIM 8192
#define MT    (N_DIM / 32)      // 256 m-tiles per (dir,b)
#define BLOCK 256
#define PPW   2                 // n-tiles per wave
#define NBLK  1024              // partial blocks

typedef short  bf16x8 __attribute__((ext_vector_type(8)));
typedef float  f32x16 __attribute__((ext_vector_type(16)));

__device__ __forceinline__ unsigned short bf16_rne(float f) {
    unsigned int u = __float_as_uint(f);
    u += 0x7fffu + ((u >> 16) & 1u);
    return (unsigned short)(u >> 16);
}
__device__ __forceinline__ float bf16f(unsigned short h) {
    return __uint_as_float(((unsigned int)h) << 16);
}

// Pack B-fragments for both directions. Layout: 16-byte frags indexed
// [dirb][mtile][half][m32] so a wave's 64 lanes read 1024 contiguous bytes.
__global__ __launch_bounds__(256) void chamfer_prep(
    const float* __restrict__ pred, const float* __restrict__ gt,
    unsigned short* __restrict__ bpack, float* __restrict__ out)
{
    const int i   = blockIdx.x * 256 + threadIdx.x;  // 0 .. 2*B*N-1
    if (i == 0) out[0] = 0.0f;
    const int dir = i >> 16;
    const int bm  = i & 0xFFFF;                      // b*N + m
    const float* dst = dir ? pred : gt;
    const float x = dst[3*bm+0], y = dst[3*bm+1], z = dst[3*bm+2];
    const unsigned short hx = bf16_rne(x), hy = bf16_rne(y), hz = bf16_rne(z);
    const unsigned short lx = bf16_rne(x - bf16f(hx));
    const unsigned short ly = bf16_rne(y - bf16f(hy));
    const unsigned short lz = bf16_rne(z - bf16f(hz));
    const float gn = x*x + y*y + z*z;
    const unsigned short gnh = bf16_rne(gn), gnl = bf16_rne(gn - bf16f(gnh));
    const unsigned short one = 0x3F80;

    const int b  = bm >> 13, m = bm & (N_DIM - 1);
    const int mt = m >> 5,   c = m & 31;
    const int dirb = (dir << 3) | b;
    unsigned short* p0 = bpack + ((size_t)(dirb * MT + mt) * 64 + c) * 8;
    unsigned short* p1 = p0 + 32 * 8;
    // half0 = k0..7 : gh(xyz) gl(xyz) gh(x,y) ; half1 = k8..15 : gh(z) 1 1 gnh gnl 0 0 0
    bf16x8 h0 = {(short)hx,(short)hy,(short)hz,(short)lx,(short)ly,(short)lz,(short)hx,(short)hy};
    bf16x8 h1 = {(short)hz,(short)one,(short)one,(short)gnh,(short)gnl,0,0,0};
    *(bf16x8*)p0 = h0;
    *(bf16x8*)p1 = h1;
}

__global__ __launch_bounds__(BLOCK, 4) void chamfer_partial(
    const float* __restrict__ pred, const float* __restrict__ gt,
    const bf16x8* __restrict__ bpack, float* __restrict__ part)
{
    __shared__ float cbuf[PPW * 16 * 128];  // 16 KB combine buffer (epilogue only)
    __shared__ float wsum[2];
    const int dirb = blockIdx.x;            // low grid bits -> XCD = dirb%8
    const int dir  = dirb >> 3, b = dirb & 7;
    const int w    = threadIdx.x >> 6, lane = threadIdx.x & 63;
    const int halfk = lane >> 5,  col = lane & 31;
    const int nsub = w & 1;                 // which n-tile pair
    const int mh   = w >> 1;                // m-half: 0 -> tiles 0..127, 1 -> 128..255

    const float* src  = dir ? gt : pred;
    const float* srcb = src + (size_t)b * N_DIM * 3;

    // A fragments for this wave's PPW n-tiles (row = col, k-half = halfk).
    bf16x8 afrag[PPW];
    #pragma unroll
    for (int p = 0; p < PPW; ++p) {
        const int ntile = blockIdx.y * 4 + nsub * 2 + p;
        const int n = ntile * 32 + col;
        const float x = srcb[3*n+0], y = srcb[3*n+1], z = srcb[3*n+2];
        const float ax = -2.f*x, ay = -2.f*y, az = -2.f*z;
        const unsigned short ahx = bf16_rne(ax), ahy = bf16_rne(ay), ahz = bf16_rne(az);
        const unsigned short alx = bf16_rne(ax - bf16f(ahx));
        const unsigned short aly = bf16_rne(ay - bf16f(ahy));
        const unsigned short alz = bf16_rne(az - bf16f(ahz));
        const float pn = x*x + y*y + z*z;
        const unsigned short pnh = bf16_rne(pn), pnl = bf16_rne(pn - bf16f(pnh));
        const unsigned short one = 0x3F80;
        bf16x8 a0 = {(short)ahx,(short)ahy,(short)ahz,(short)ahx,(short)ahy,(short)ahz,(short)alx,(short)aly};
        bf16x8 a1 = {(short)alz,(short)pnh,(short)pnl,(short)one,(short)one,0,0,0};
        afrag[p] = (halfk == 0) ? a0 : a1;
    }

    float best[PPW][16];
    #pragma unroll
    for (int p = 0; p < PPW; ++p)
        #pragma unroll
        for (int r = 0; r < 16; ++r) best[p][r] = 1e30f;

    // This wave's B-fragment stream: 128 m-tiles, 1 KB (wave) per tile,
    // coalesced dwordx4 per lane, L2-resident.
    const bf16x8* bw = bpack + (size_t)dirb * (MT * 64) + (size_t)(mh * 128) * 64 + lane;

    // MFMA pair in asm (C = inline 0; s_nop 7+3 inside covers the
    // MFMA->VALU read hazard), then per-element asm v_min3. R15-proven.
#define FOLD(c0_, c1_) { \
        f32x16 d0, d1; \
        asm volatile( \
            "v_mfma_f32_32x32x16_bf16 %0, %2, %3, 0\n\t" \
            "v_mfma_f32_32x32x16_bf16 %1, %2, %4, 0\n\t" \
            "s_nop 7\n\t" \
            "s_nop 3" \
            : "=&v"(d0), "=&v"(d1) \
            : "v"(afrag[0]), "v"(c0_), "v"(c1_)); \
        __builtin_amdgcn_sched_barrier(0x34); \
        _Pragma("unroll") \
        for (int r = 0; r < 16; ++r) \
            asm("v_min3_f32 %0, %0, %1, %2" \
                : "+v"(best[0][r]) : "v"(d0[r]), "v"(d1[r])); \
        f32x16 d2, d3; \
        asm volatile( \
            "v_mfma_f32_32x32x16_bf16 %0, %2, %3, 0\n\t" \
            "v_mfma_f32_32x32x16_bf16 %1, %2, %4, 0\n\t" \
            "s_nop 7\n\t" \
            "s_nop 3" \
            : "=&v"(d2), "=&v"(d3) \
            : "v"(afrag[1]), "v"(c0_), "v"(c1_)); \
        __builtin_amdgcn_sched_barrier(0x34); \
        _Pragma("unroll") \
        for (int r = 0; r < 16; ++r) \
            asm("v_min3_f32 %0, %0, %1, %2" \
                : "+v"(best[1][r]) : "v"(d2[r]), "v"(d3[r])); \
    }

    // Copy-free x2 ping-pong: 64 tile-pair phases (R15-proven, 43.7us).
    bf16x8 cA0 = bw[0],   cA1 = bw[64];    // P0
    bf16x8 cB0 = bw[128], cB1 = bw[192];   // P1
    bw += 256;
    for (int t = 0; t < 31; ++t) {
        FOLD(cA0, cA1);                    // fold P{2t}
        cA0 = bw[0];   cA1 = bw[64];       // load P{2t+2}
        FOLD(cB0, cB1);                    // fold P{2t+1}
        cB0 = bw[128]; cB1 = bw[192];      // load P{2t+3}
        bw += 256;
    }
    FOLD(cA0, cA1);                        // P62
    FOLD(cB0, cB1);                        // P63

    // Combine the two m-halves: waves 2,3 export best[] through LDS,
    // waves 0,1 min-combine. Lanes contiguous -> conflict-free.
    if (mh == 1) {
        #pragma unroll
        for (int p = 0; p < PPW; ++p)
            #pragma unroll
            for (int r = 0; r < 16; ++r)
                cbuf[(p * 16 + r) * 128 + nsub * 64 + lane] = best[p][r];
    }
    __syncthreads();
    if (mh == 0) {
        float bsum = 0.f;
        #pragma unroll
        for (int p = 0; p < PPW; ++p) {
            float s = 0.f;
            #pragma unroll
            for (int r = 0; r < 16; ++r) {
                float v = fminf(best[p][r], cbuf[(p * 16 + r) * 128 + nsub * 64 + lane]);
                v = fminf(v, __shfl_xor(v, 1,  64));
                v = fminf(v, __shfl_xor(v, 2,  64));
                v = fminf(v, __shfl_xor(v, 4,  64));
                v = fminf(v, __shfl_xor(v, 8,  64));
                v = fminf(v, __shfl_xor(v, 16, 64));
                s += v;                       // 16 final row-mins of this k-half
            }
            bsum += s + __shfl_xor(s, 32, 64);  // add other k-half's 16 rows
        }
        if (lane == 0) wsum[nsub] = bsum;
    }
    __syncthreads();
    // NO atomic: plain store of the unscaled block sum (no tail serialization).
    if (threadIdx.x == 0)
        part[blockIdx.y * 16 + blockIdx.x] = wsum[0] + wsum[1];
}

// Single-block finalize: sum 1024 partials, scale, write out[0].
__global__ __launch_bounds__(256) void chamfer_final(
    const float* __restrict__ part, float* __restrict__ out)
{
    float s = 0.f;
    #pragma unroll
    for (int i = 0; i < NBLK / 256; ++i)
        s += part[i * 256 + threadIdx.x];
    s += __shfl_xor(s, 1,  64);
    s += __shfl_xor(s, 2,  64);
    s += __shfl_xor(s, 4,  64);
    s += __shfl_xor(s, 8,  64);
    s += __shfl_xor(s, 16, 64);
    s += __shfl_xor(s, 32, 64);
    __shared__ float ws4[4];
    const int w = threadIdx.x >> 6, lane = threadIdx.x & 63;
    if (lane == 0) ws4[w] = s;
    __syncthreads();
    if (threadIdx.x == 0) {
        const float scale = 100.0f * 0.5f / ((float)B_DIM * (float)N_DIM);
        out[0] = (ws4[0] + ws4[1] + ws4[2] + ws4[3]) * scale;
    }
}

extern "C" void kernel_launch(void* const* d_in, const int* in_sizes, int n_in,
                              void* d_out, int out_size, void* d_ws, size_t ws_size,
                              hipStream_t stream) {
    const float* pred = (const float*)d_in[0];
    const float* gt   = (const float*)d_in[1];
    float* out = (float*)d_out;
    unsigned short* bpack = (unsigned short*)d_ws;               // 4 MiB
    float* part = (float*)((char*)d_ws + ((size_t)4 << 20));     // 4 KiB

    chamfer_prep<<<(2 * B_DIM * N_DIM) / 256, 256, 0, stream>>>(pred, gt, bpack, out);

    // dirb x n-chunks(128 pts) = 16 x 64 = 1024 blocks, 4 indep waves each
    dim3 grid(16, N_DIM / 128);
    chamfer_partial<<<grid, BLOCK, 0, stream>>>(pred, gt, (const bf16x8*)bpack, part);

    chamfer_final<<<1, 256, 0, stream>>>(part, out);
}

// Round 18
// 94.125 us; speedup vs baseline: 1.0128x; 1.0128x over previous
//
#include <hip/hip_runtime.h>

// Chamfer distance: B=8, N=M=8192, D=3, fp32, via bf16 split-precision MFMA.
// R25: cross-fit of R15/R16 per-phase walls yields a consistent HW constant:
//   dependent-use latency of v_mfma_f32_32x32x16_bf16 ~ 165 cyc (vs 32-cyc
//   pipe occupancy). Every prior FOLD consumed d ~16-40 cyc after issue ->
//   ~130 cyc stall per MFMA-pair per wave; 2-4 waves/SIMD can't cover it.
//   Explains all 9 nulls (occupancy/traffic/stagger/atomic don't change
//   producer-consumer distance). R18's batch test was void (VGPR_Count 84 =
//   168 arch < 246 live -> remat/AGPR + in-asm nops between pairs).
//   Fix: ONE-PHASE-DEEP SOFTWARE PIPELINE. Per phase: issue all 4 MFMAs
//   (one asm block, dE/dO alternation), then min3 the PREVIOUS phase's
//   quad. Distance = 32 min3 + issue + reload + 2-wave interleave ~ 150-250
//   cyc >= L; no in-loop s_nops (epilogue nops for final consumes).
//   Regs: dE 64 + dO 64 + best 32 + cA/cB 32 + afrag 16 ~ 215 ->
//   launch_bounds(256,2) (cap 256), grid 16x32 = 512 blocks = 2 waves/SIMD,
//   each wave streams all 256 m-tiles (128 pair-phases; B-traffic 128MB).
//   No m-split; no atomics (part[]+final, R24-proven).

#define B_DIM 8
#define N_DIM 8192
#define MT    (N_DIM / 32)      // 256 m-tiles per (dir,b)
#define BLOCK 256
#define PPW   2                 // n-tiles per wave
#define NBLK  512               // partial blocks

typedef short  bf16x8 __attribute__((ext_vector_type(8)));
typedef float  f32x16 __attribute__((ext_vector_type(16)));

__device__ __forceinline__ unsigned short bf16_rne(float f) {
    unsigned int u = __float_as_uint(f);
    u += 0x7fffu + ((u >> 16) & 1u);
    return (unsigned short)(u >> 16);
}
__device__ __forceinline__ float bf16f(unsigned short h) {
    return __uint_as_float(((unsigned int)h) << 16);
}

// Pack B-fragments for both directions. Layout: 16-byte frags indexed
// [dirb][mtile][half][m32] so a wave's 64 lanes read 1024 contiguous bytes.
__global__ __launch_bounds__(256) void chamfer_prep(
    const float* __restrict__ pred, const float* __restrict__ gt,
    unsigned short* __restrict__ bpack, float* __restrict__ out)
{
    const int i   = blockIdx.x * 256 + threadIdx.x;  // 0 .. 2*B*N-1
    if (i == 0) out[0] = 0.0f;
    const int dir = i >> 16;
    const int bm  = i & 0xFFFF;                      // b*N + m
    const float* dst = dir ? pred : gt;
    const float x = dst[3*bm+0], y = dst[3*bm+1], z = dst[3*bm+2];
    const unsigned short hx = bf16_rne(x), hy = bf16_rne(y), hz = bf16_rne(z);
    const unsigned short lx = bf16_rne(x - bf16f(hx));
    const unsigned short ly = bf16_rne(y - bf16f(hy));
    const unsigned short lz = bf16_rne(z - bf16f(hz));
    const float gn = x*x + y*y + z*z;
    const unsigned short gnh = bf16_rne(gn), gnl = bf16_rne(gn - bf16f(gnh));
    const unsigned short one = 0x3F80;

    const int b  = bm >> 13, m = bm & (N_DIM - 1);
    const int mt = m >> 5,   c = m & 31;
    const int dirb = (dir << 3) | b;
    unsigned short* p0 = bpack + ((size_t)(dirb * MT + mt) * 64 + c) * 8;
    unsigned short* p1 = p0 + 32 * 8;
    // half0 = k0..7 : gh(xyz) gl(xyz) gh(x,y) ; half1 = k8..15 : gh(z) 1 1 gnh gnl 0 0 0
    bf16x8 h0 = {(short)hx,(short)hy,(short)hz,(short)lx,(short)ly,(short)lz,(short)hx,(short)hy};
    bf16x8 h1 = {(short)hz,(short)one,(short)one,(short)gnh,(short)gnl,0,0,0};
    *(bf16x8*)p0 = h0;
    *(bf16x8*)p1 = h1;
}

__global__ __launch_bounds__(BLOCK, 2) void chamfer_partial(
    const float* __restrict__ pred, const float* __restrict__ gt,
    const bf16x8* __restrict__ bpack, float* __restrict__ part)
{
    __shared__ float wsum[4];
    const int dirb = blockIdx.x;            // low grid bits -> XCD = dirb%8
    const int dir  = dirb >> 3, b = dirb & 7;
    const int w    = threadIdx.x >> 6, lane = threadIdx.x & 63;
    const int halfk = lane >> 5,  col = lane & 31;

    const float* src  = dir ? gt : pred;
    const float* srcb = src + (size_t)b * N_DIM * 3;

    // A fragments for this wave's PPW n-tiles (row = col, k-half = halfk).
    bf16x8 afrag[PPW];
    #pragma unroll
    for (int p = 0; p < PPW; ++p) {
        const int ntile = blockIdx.y * 8 + w * 2 + p;   // 8 tiles per block
        const int n = ntile * 32 + col;
        const float x = srcb[3*n+0], y = srcb[3*n+1], z = srcb[3*n+2];
        const float ax = -2.f*x, ay = -2.f*y, az = -2.f*z;
        const unsigned short ahx = bf16_rne(ax), ahy = bf16_rne(ay), ahz = bf16_rne(az);
        const unsigned short alx = bf16_rne(ax - bf16f(ahx));
        const unsigned short aly = bf16_rne(ay - bf16f(ahy));
        const unsigned short alz = bf16_rne(az - bf16f(ahz));
        const float pn = x*x + y*y + z*z;
        const unsigned short pnh = bf16_rne(pn), pnl = bf16_rne(pn - bf16f(pnh));
        const unsigned short one = 0x3F80;
        bf16x8 a0 = {(short)ahx,(short)ahy,(short)ahz,(short)ahx,(short)ahy,(short)ahz,(short)alx,(short)aly};
        bf16x8 a1 = {(short)alz,(short)pnh,(short)pnl,(short)one,(short)one,0,0,0};
        afrag[p] = (halfk == 0) ? a0 : a1;
    }

    float best[PPW][16];
    #pragma unroll
    for (int p = 0; p < PPW; ++p)
        #pragma unroll
        for (int r = 0; r < 16; ++r) best[p][r] = 1e30f;

    // This wave streams ALL 256 m-tiles = 128 pair-phases (256 KB, L2-res).
    const bf16x8* bq = bpack + (size_t)dirb * (MT * 64) + lane;

    // Issue all 4 MFMAs of a phase in one volatile asm block (C = inline 0,
    // no nops — consumer is one phase away, >= ~150 cyc > both the 18-state
    // hazard and the ~165-cyc dependent-use latency).
#define BATCH(q0_, q1_, q2_, q3_, c0_, c1_) \
        asm volatile( \
            "v_mfma_f32_32x32x16_bf16 %0, %4, %6, 0\n\t" \
            "v_mfma_f32_32x32x16_bf16 %1, %4, %7, 0\n\t" \
            "v_mfma_f32_32x32x16_bf16 %2, %5, %6, 0\n\t" \
            "v_mfma_f32_32x32x16_bf16 %3, %5, %7, 0" \
            : "=&v"(q0_), "=&v"(q1_), "=&v"(q2_), "=&v"(q3_) \
            : "v"(afrag[0]), "v"(afrag[1]), "v"(c0_), "v"(c1_));

    // Consume a phase's quad: 32 v_min3 (volatile -> order pinned vs BATCH).
#define MIN3Q(q0_, q1_, q2_, q3_) { \
        _Pragma("unroll") \
        for (int r = 0; r < 16; ++r) \
            asm volatile("v_min3_f32 %0, %0, %1, %2" \
                : "+v"(best[0][r]) : "v"((q0_)[r]), "v"((q1_)[r])); \
        _Pragma("unroll") \
        for (int r = 0; r < 16; ++r) \
            asm volatile("v_min3_f32 %0, %0, %1, %2" \
                : "+v"(best[1][r]) : "v"((q2_)[r]), "v"((q3_)[r])); \
    }

    f32x16 dE0, dE1, dE2, dE3;   // even-phase quad
    f32x16 dO0, dO1, dO2, dO3;   // odd-phase quad

    // Prologue: load pairs 0,1; issue phase 0.
    bf16x8 cA0 = bq[0],   cA1 = bq[64];
    bf16x8 cB0 = bq[128], cB1 = bq[192];
    BATCH(dE0, dE1, dE2, dE3, cA0, cA1);
    cA0 = bq[256]; cA1 = bq[320];          // pair 2

    for (int t = 0; t < 63; ++t) {
        BATCH(dO0, dO1, dO2, dO3, cB0, cB1);            // issue phase 2t+1
        { const bf16x8* nx = bq + ((2*t + 3) & 127) * 128;
          cB0 = nx[0]; cB1 = nx[64]; }                  // reload pair 2t+3
        MIN3Q(dE0, dE1, dE2, dE3);                      // consume phase 2t
        BATCH(dE0, dE1, dE2, dE3, cA0, cA1);            // issue phase 2t+2
        { const bf16x8* nx = bq + ((2*t + 4) & 127) * 128;
          cA0 = nx[0]; cA1 = nx[64]; }                  // reload (wraps @t=62)
        MIN3Q(dO0, dO1, dO2, dO3);                      // consume phase 2t+1
    }
    BATCH(dO0, dO1, dO2, dO3, cB0, cB1);                // issue phase 127
    MIN3Q(dE0, dE1, dE2, dE3);                          // consume phase 126
    asm volatile("s_nop 7\n\ts_nop 7\n\ts_nop 7\n\ts_nop 3");  // drain 127
    MIN3Q(dO0, dO1, dO2, dO3);                          // consume phase 127

    // Row-mins are final (full m-range per wave): lane-reduce and sum.
    float bsum = 0.f;
    #pragma unroll
    for (int p = 0; p < PPW; ++p) {
        float s = 0.f;
        #pragma unroll
        for (int r = 0; r < 16; ++r) {
            float v = best[p][r];
            v = fminf(v, __shfl_xor(v, 1,  64));
            v = fminf(v, __shfl_xor(v, 2,  64));
            v = fminf(v, __shfl_xor(v, 4,  64));
            v = fminf(v, __shfl_xor(v, 8,  64));
            v = fminf(v, __shfl_xor(v, 16, 64));
            s += v;                       // 16 final row-mins of this half
        }
        bsum += s + __shfl_xor(s, 32, 64);  // add other half's 16 rows
    }
    if (lane == 0) wsum[w] = bsum;
    __syncthreads();
    // NO atomic: plain store of the unscaled block sum.
    if (threadIdx.x == 0)
        part[blockIdx.y * 16 + blockIdx.x] =
            wsum[0] + wsum[1] + wsum[2] + wsum[3];
}

// Single-block finalize: sum 512 partials, scale, write out[0].
__global__ __launch_bounds__(256) void chamfer_final(
    const float* __restrict__ part, float* __restrict__ out)
{
    float s = part[threadIdx.x] + part[256 + threadIdx.x];
    s += __shfl_xor(s, 1,  64);
    s += __shfl_xor(s, 2,  64);
    s += __shfl_xor(s, 4,  64);
    s += __shfl_xor(s, 8,  64);
    s += __shfl_xor(s, 16, 64);
    s += __shfl_xor(s, 32, 64);
    __shared__ float ws4[4];
    const int w = threadIdx.x >> 6, lane = threadIdx.x & 63;
    if (lane == 0) ws4[w] = s;
    __syncthreads();
    if (threadIdx.x == 0) {
        const float scale = 100.0f * 0.5f / ((float)B_DIM * (float)N_DIM);
        out[0] = (ws4[0] + ws4[1] + ws4[2] + ws4[3]) * scale;
    }
}

extern "C" void kernel_launch(void* const* d_in, const int* in_sizes, int n_in,
                              void* d_out, int out_size, void* d_ws, size_t ws_size,
                              hipStream_t stream) {
    const float* pred = (const float*)d_in[0];
    const float* gt   = (const float*)d_in[1];
    float* out = (float*)d_out;
    unsigned short* bpack = (unsigned short*)d_ws;               // 4 MiB
    float* part = (float*)((char*)d_ws + ((size_t)4 << 20));     // 2 KiB

    chamfer_prep<<<(2 * B_DIM * N_DIM) / 256, 256, 0, stream>>>(pred, gt, bpack, out);

    // dirb x n-chunks(256 pts) = 16 x 32 = 512 blocks, 2/CU, 2 waves/SIMD
    dim3 grid(16, N_DIM / 256);
    chamfer_partial<<<grid, BLOCK, 0, stream>>>(pred, gt, (const bf16x8*)bpack, part);

    chamfer_final<<<1, 256, 0, stream>>>(part, out);
}

// Round 19
// 92.750 us; speedup vs baseline: 1.0278x; 1.0148x over previous
//
#include <hip/hip_runtime.h>

// Chamfer distance: B=8, N=M=8192, D=3, fp32, via bf16 split-precision MFMA.
// R26 = lock-in of R19, the session's best-measured total (92.77us).
//   Investigation closed after 10 structural nulls (R15-R25): partial wall
//   ~41-44us is invariant to MFMA count (512-2048/SIMD), load bytes
//   (256KB-2MB/SIMD), waves/SIMD (2-4.4), prefetch depth (0.5-3 phases),
//   consumer distance (16cyc-1 phase), stagger, atomics, launch bounds.
//   No controllable pipe explains it; counters far from ceilings in all
//   variants. Dominant remaining hypothesis: external limiter — each timed
//   iteration starts with the harness's 268MB ws re-poison fill (~44us at
//   6.5TB/s, in-stream), and the partial runs in the post-fill clock/power
//   recovery window. Total = fill(44) + prep(3) + partial(41) + final/gaps
//   ≈ 93us = the practical plateau for this harness.
//   Kernel: two-pass (dir0/dir1), PPW=4, depth-3 copy-free ping-pong
//   (4 pairs cA..cD, reload-after-kill, consume 3 phases later), asm MFMA
//   pair + s_nop 7/3 + v_min3 "+v" FOLD (R12/R14-proven correct), m-half
//   split across wave pairs, LDS combine, one atomicAdd per block.

#define B_DIM 8
#define N_DIM 8192
#define MT    (N_DIM / 32)      // 256 m-tiles per (dir,b)
#define BLOCK 256
#define PPW   4                 // n-tiles per wave

typedef short  bf16x8 __attribute__((ext_vector_type(8)));
typedef float  f32x16 __attribute__((ext_vector_type(16)));

__device__ __forceinline__ unsigned short bf16_rne(float f) {
    unsigned int u = __float_as_uint(f);
    u += 0x7fffu + ((u >> 16) & 1u);
    return (unsigned short)(u >> 16);
}
__device__ __forceinline__ float bf16f(unsigned short h) {
    return __uint_as_float(((unsigned int)h) << 16);
}

// Pack B-fragments for both directions. Layout: 16-byte frags indexed
// [dirb][mtile][half][m32] so a wave's 64 lanes read 1024 contiguous bytes.
__global__ __launch_bounds__(256) void chamfer_prep(
    const float* __restrict__ pred, const float* __restrict__ gt,
    unsigned short* __restrict__ bpack, float* __restrict__ out)
{
    const int i   = blockIdx.x * 256 + threadIdx.x;  // 0 .. 2*B*N-1
    if (i == 0) out[0] = 0.0f;
    const int dir = i >> 16;
    const int bm  = i & 0xFFFF;                      // b*N + m
    const float* dst = dir ? pred : gt;
    const float x = dst[3*bm+0], y = dst[3*bm+1], z = dst[3*bm+2];
    const unsigned short hx = bf16_rne(x), hy = bf16_rne(y), hz = bf16_rne(z);
    const unsigned short lx = bf16_rne(x - bf16f(hx));
    const unsigned short ly = bf16_rne(y - bf16f(hy));
    const unsigned short lz = bf16_rne(z - bf16f(hz));
    const float gn = x*x + y*y + z*z;
    const unsigned short gnh = bf16_rne(gn), gnl = bf16_rne(gn - bf16f(gnh));
    const unsigned short one = 0x3F80;

    const int b  = bm >> 13, m = bm & (N_DIM - 1);
    const int mt = m >> 5,   c = m & 31;
    const int dirb = (dir << 3) | b;
    unsigned short* p0 = bpack + ((size_t)(dirb * MT + mt) * 64 + c) * 8;
    unsigned short* p1 = p0 + 32 * 8;
    // half0 = k0..7 : gh(xyz) gl(xyz) gh(x,y) ; half1 = k8..15 : gh(z) 1 1 gnh gnl 0 0 0
    bf16x8 h0 = {(short)hx,(short)hy,(short)hz,(short)lx,(short)ly,(short)lz,(short)hx,(short)hy};
    bf16x8 h1 = {(short)hz,(short)one,(short)one,(short)gnh,(short)gnl,0,0,0};
    *(bf16x8*)p0 = h0;
    *(bf16x8*)p1 = h1;
}

__global__ __launch_bounds__(BLOCK, 2) void chamfer_partial(
    const float* __restrict__ pred, const float* __restrict__ gt,
    const bf16x8* __restrict__ bpack, float* __restrict__ out)
{
    __shared__ float cbuf[PPW * 16 * 128];  // 32 KB combine buffer (epilogue only)
    __shared__ float wsum[2];
    const int dirb = blockIdx.x;            // low grid bits -> XCD = dirb%8
    const int dir  = dirb >> 3, b = dirb & 7;
    const int w    = threadIdx.x >> 6, lane = threadIdx.x & 63;
    const int halfk = lane >> 5,  col = lane & 31;
    const int nsub = w & 1;                 // which n-tile quad
    const int mh   = w >> 1;                // m-half: 0 -> tiles 0..127, 1 -> 128..255

    const float* src  = dir ? gt : pred;
    const float* srcb = src + (size_t)b * N_DIM * 3;

    // A fragments for this wave's PPW n-tiles (row = col, k-half = halfk).
    bf16x8 afrag[PPW];
    #pragma unroll
    for (int p = 0; p < PPW; ++p) {
        const int ntile = blockIdx.y * 8 + nsub * PPW + p;
        const int n = ntile * 32 + col;
        const float x = srcb[3*n+0], y = srcb[3*n+1], z = srcb[3*n+2];
        const float ax = -2.f*x, ay = -2.f*y, az = -2.f*z;
        const unsigned short ahx = bf16_rne(ax), ahy = bf16_rne(ay), ahz = bf16_rne(az);
        const unsigned short alx = bf16_rne(ax - bf16f(ahx));
        const unsigned short aly = bf16_rne(ay - bf16f(ahy));
        const unsigned short alz = bf16_rne(az - bf16f(ahz));
        const float pn = x*x + y*y + z*z;
        const unsigned short pnh = bf16_rne(pn), pnl = bf16_rne(pn - bf16f(pnh));
        const unsigned short one = 0x3F80;
        bf16x8 a0 = {(short)ahx,(short)ahy,(short)ahz,(short)ahx,(short)ahy,(short)ahz,(short)alx,(short)aly};
        bf16x8 a1 = {(short)alz,(short)pnh,(short)pnl,(short)one,(short)one,0,0,0};
        afrag[p] = (halfk == 0) ? a0 : a1;
    }

    float best[PPW][16];
    #pragma unroll
    for (int p = 0; p < PPW; ++p)
        #pragma unroll
        for (int r = 0; r < 16; ++r) best[p][r] = 1e30f;

    // This wave's B-fragment stream: 128 m-tiles, 1 KB (wave) per tile,
    // coalesced dwordx4 per lane.
    const bf16x8* bw = bpack + (size_t)dirb * (MT * 64) + (size_t)(mh * 128) * 64 + lane;

    // Per n-tile p: MFMA pair in asm (C = inline 0; s_nop 7+3 in-asm
    // covers the MFMA->VALU read hazard), then per-element asm v_min3 on
    // arch VGPRs. R14/R16-proven correct.
#define FOLD(c0_, c1_) { \
        _Pragma("unroll") \
        for (int p = 0; p < PPW; ++p) { \
            f32x16 d0, d1; \
            asm volatile( \
                "v_mfma_f32_32x32x16_bf16 %0, %2, %3, 0\n\t" \
                "v_mfma_f32_32x32x16_bf16 %1, %2, %4, 0\n\t" \
                "s_nop 7\n\t" \
                "s_nop 3" \
                : "=&v"(d0), "=&v"(d1) \
                : "v"(afrag[p]), "v"(c0_), "v"(c1_)); \
            __builtin_amdgcn_sched_barrier(0x34); \
            _Pragma("unroll") \
            for (int r = 0; r < 16; ++r) \
                asm("v_min3_f32 %0, %0, %1, %2" \
                    : "+v"(best[p][r]) : "v"(d0[r]), "v"(d1[r])); \
        } \
    }

    // Depth-3 copy-free ping-pong: 64 tile-pair phases P0..P63 across four
    // register pairs. Each pair reloads into ITS OWN registers right after
    // the FOLD that kills it (WAR orders load after consume) and is next
    // consumed THREE phases later.
    bf16x8 cA0 = bw[0],   cA1 = bw[64];    // P0
    bf16x8 cB0 = bw[128], cB1 = bw[192];   // P1
    bf16x8 cC0 = bw[256], cC1 = bw[320];   // P2
    bf16x8 cD0 = bw[384], cD1 = bw[448];   // P3
    bw += 512;
    for (int t = 0; t < 15; ++t) {
        FOLD(cA0, cA1);  cA0 = bw[0];   cA1 = bw[64];    // load P{4t+4}
        FOLD(cB0, cB1);  cB0 = bw[128]; cB1 = bw[192];   // load P{4t+5}
        FOLD(cC0, cC1);  cC0 = bw[256]; cC1 = bw[320];   // load P{4t+6}
        FOLD(cD0, cD1);  cD0 = bw[384]; cD1 = bw[448];   // load P{4t+7}
        bw += 512;
    }
    FOLD(cA0, cA1);                        // P60
    FOLD(cB0, cB1);                        // P61
    FOLD(cC0, cC1);                        // P62
    FOLD(cD0, cD1);                        // P63

    // Combine the two m-halves: waves 2,3 export best[] through LDS,
    // waves 0,1 min-combine. Lanes contiguous -> conflict-free.
    if (mh == 1) {
        #pragma unroll
        for (int p = 0; p < PPW; ++p)
            #pragma unroll
            for (int r = 0; r < 16; ++r)
                cbuf[(p * 16 + r) * 128 + nsub * 64 + lane] = best[p][r];
    }
    __syncthreads();
    if (mh == 0) {
        float bsum = 0.f;
        #pragma unroll
        for (int p = 0; p < PPW; ++p) {
            float s = 0.f;
            #pragma unroll
            for (int r = 0; r < 16; ++r) {
                float v = fminf(best[p][r], cbuf[(p * 16 + r) * 128 + nsub * 64 + lane]);
                v = fminf(v, __shfl_xor(v, 1,  64));
                v = fminf(v, __shfl_xor(v, 2,  64));
                v = fminf(v, __shfl_xor(v, 4,  64));
                v = fminf(v, __shfl_xor(v, 8,  64));
                v = fminf(v, __shfl_xor(v, 16, 64));
                s += v;                       // 16 final row-mins of this k-half
            }
            bsum += s + __shfl_xor(s, 32, 64);  // add other k-half's 16 rows
        }
        if (lane == 0) wsum[nsub] = bsum;
    }
    __syncthreads();
    if (threadIdx.x == 0) {
        const float scale = 100.0f * 0.5f / ((float)B_DIM * (float)N_DIM);
        atomicAdd(out, (wsum[0] + wsum[1]) * scale);
    }
}

extern "C" void kernel_launch(void* const* d_in, const int* in_sizes, int n_in,
                              void* d_out, int out_size, void* d_ws, size_t ws_size,
                              hipStream_t stream) {
    const float* pred = (const float*)d_in[0];
    const float* gt   = (const float*)d_in[1];
    float* out = (float*)d_out;
    unsigned short* bpack = (unsigned short*)d_ws;   // 4 MiB

    chamfer_prep<<<(2 * B_DIM * N_DIM) / 256, 256, 0, stream>>>(pred, gt, bpack, out);

    // dirb x n-chunks(256 pts) = 16 x 32 = 512 blocks, 2/CU, 4 indep waves
    dim3 grid(16, N_DIM / 256);
    chamfer_partial<<<grid, BLOCK, 0, stream>>>(pred, gt, (const bf16x8*)bpack, out);
}